// Round 3
// baseline (226.909 us; speedup 1.0000x reference)
//
#include <hip/hip_runtime.h>

#define A_N   4096
#define EMBED 128
#define MAXO  16
#define DEG   8
#define OBSD  8
#define ORIG  18
#define KCAND 128          // DEG*MAXO candidates per agent
#define G     8            // agents per block
#define NBLK  (A_N / G)    // 512
#define NTHR  256

// ---------------------------------------------------------------------------
// Kernel A: 8 source agents per block.
//   msg (64 rows x 18) -> h=relu(msg@W1+b1) -> segment-sum(8) -> S (128c x 8g)
//   enc = S@W2+b2 -> npred = argmax(enc@Ws+bs) -> elems_base = enc@Wx+bx
// Column-parallel: thread (col, half) computes output column `col` for 4
// agents at once; LDS activations stored [c][g] so 4 agents read as float4.
// ---------------------------------------------------------------------------
__global__ __launch_bounds__(NTHR) void enc8_kernel(
    const float* __restrict__ obj_x, const float* __restrict__ obj_pos,
    const float* __restrict__ agent_pos,
    const float* __restrict__ enc_W1, const float* __restrict__ enc_b1,
    const float* __restrict__ enc_W2, const float* __restrict__ enc_b2,
    const float* __restrict__ mdec_Ws, const float* __restrict__ mdec_bs,
    const float* __restrict__ mdec_Wx, const float* __restrict__ mdec_bx,
    const int* __restrict__ obs_edge,
    float* __restrict__ elems_base, int* __restrict__ npred_out)
{
    const int blk = blockIdx.x, tid = threadIdx.x;
    const int i0  = blk * G;
    const int col = tid & 127, half = tid >> 7;

    __shared__ float msg[G * OBSD][20];      // 64 rows x 18 (pad 20)
    __shared__ int   on[G][OBSD];
    __shared__ float Sg[EMBED][G];
    __shared__ float Eg[EMBED][G];
    __shared__ float lg[G][MAXO + 1];

    // --- stage object indices, then messages ---
    if (tid < G * OBSD) {
        const int g = tid >> 3, d = tid & 7;
        on[g][d] = obs_edge[A_N * OBSD + (i0 + g) * OBSD + d];
    }
    __syncthreads();
    for (int idx = tid; idx < G * OBSD * ORIG; idx += NTHR) {
        const int r = idx / ORIG, c = idx % ORIG;
        const int g = r >> 3, d = r & 7;
        const int o = on[g][d];
        float v;
        if (c < 16) v = obj_x[o * 16 + c];
        else        v = obj_pos[o * 2 + (c - 16)] - agent_pos[(i0 + g) * 2 + (c - 16)];
        msg[r][c] = v;
    }
    __syncthreads();

    // --- h = relu(msg@W1+b1), segment-sum by agent ---
    {
        float w1[ORIG];
#pragma unroll
        for (int c = 0; c < ORIG; ++c) w1[c] = enc_W1[c * EMBED + col];
        const float b1 = enc_b1[col];
        int r = 32 * half;
        for (int gg = 0; gg < 4; ++gg) {
            float acc = 0.f;
#pragma unroll
            for (int d = 0; d < 8; ++d, ++r) {
                const float4* mr = (const float4*)&msg[r][0];
                const float4 m0 = mr[0], m1 = mr[1], m2 = mr[2], m3 = mr[3];
                const float2 m4 = *(const float2*)&msg[r][16];
                float h = b1
                    + m0.x*w1[0]  + m0.y*w1[1]  + m0.z*w1[2]  + m0.w*w1[3]
                    + m1.x*w1[4]  + m1.y*w1[5]  + m1.z*w1[6]  + m1.w*w1[7]
                    + m2.x*w1[8]  + m2.y*w1[9]  + m2.z*w1[10] + m2.w*w1[11]
                    + m3.x*w1[12] + m3.y*w1[13] + m3.z*w1[14] + m3.w*w1[15]
                    + m4.x*w1[16] + m4.y*w1[17];
                acc += fmaxf(h, 0.f);
            }
            Sg[col][4 * half + gg] = acc;
        }
    }
    __syncthreads();

    // --- enc = S@W2 + b2 ---
    {
        const float b2 = enc_b2[col];
        float e0 = b2, e1 = b2, e2 = b2, e3 = b2;
        for (int c = 0; c < EMBED; ++c) {
            const float4 s = *(const float4*)&Sg[c][4 * half];
            const float  w = enc_W2[c * EMBED + col];
            e0 += s.x * w; e1 += s.y * w; e2 += s.z * w; e3 += s.w * w;
        }
        Eg[col][4 * half + 0] = e0; Eg[col][4 * half + 1] = e1;
        Eg[col][4 * half + 2] = e2; Eg[col][4 * half + 3] = e3;
    }
    __syncthreads();

    // --- npred = argmax(enc@Ws + bs) ---
    if (tid < G * (MAXO + 1)) {
        const int g = tid / (MAXO + 1), q = tid % (MAXO + 1);
        float v = mdec_bs[q];
        for (int c = 0; c < EMBED; ++c) v += Eg[c][g] * mdec_Ws[c * (MAXO + 1) + q];
        lg[g][q] = v;
    }
    __syncthreads();
    if (tid < G) {
        int best = 0; float bv = lg[tid][0];
        for (int q = 1; q <= MAXO; ++q) if (lg[tid][q] > bv) { bv = lg[tid][q]; best = q; }
        npred_out[i0 + tid] = best;
    }

    // --- elems_base = enc@Wx + bx ---
    for (int e = col; e < MAXO * ORIG; e += 128) {
        const float bx = mdec_bx[e];
        float a0 = bx, a1 = bx, a2 = bx, a3 = bx;
        for (int c = 0; c < EMBED; ++c) {
            const float4 s = *(const float4*)&Eg[c][4 * half];
            const float  w = mdec_Wx[c * (MAXO * ORIG) + e];
            a0 += s.x * w; a1 += s.y * w; a2 += s.z * w; a3 += s.w * w;
        }
        elems_base[(size_t)(i0 + 4 * half + 0) * (MAXO * ORIG) + e] = a0;
        elems_base[(size_t)(i0 + 4 * half + 1) * (MAXO * ORIG) + e] = a1;
        elems_base[(size_t)(i0 + 4 * half + 2) * (MAXO * ORIG) + e] = a2;
        elems_base[(size_t)(i0 + 4 * half + 3) * (MAXO * ORIG) + e] = a3;
    }
}

// ---------------------------------------------------------------------------
// Kernel B: 8 target agents per block.
//   positions+valid -> dedup (<0.02, earlier-valid) -> cap 15 -> compact kept
//   list -> gather kept features -> hsum (<=15 rows) -> merged -> heads.
// ---------------------------------------------------------------------------
__global__ __launch_bounds__(NTHR) void merge8_kernel(
    const float* __restrict__ agent_pos,
    const float* __restrict__ menc_W1, const float* __restrict__ menc_b1,
    const float* __restrict__ menc_W2, const float* __restrict__ menc_b2,
    const float* __restrict__ dec_Ws, const float* __restrict__ dec_bs,
    const float* __restrict__ dec_Wx, const float* __restrict__ dec_bx,
    const int* __restrict__ comm_edge,
    const float* __restrict__ elems_base, const int* __restrict__ npred,
    float* __restrict__ out_dec, float* __restrict__ out_batch,
    float* __restrict__ out_mask)
{
    const int blk = blockIdx.x, tid = threadIdx.x;
    const int i0  = blk * G;
    const int col = tid & 127, half = tid >> 7;

    __shared__ float2        pxy[G][KCAND];        // 8 KB
    __shared__ unsigned char vldA[G][KCAND];       // 1 KB
    __shared__ int   jn[G][DEG];
    __shared__ float relx[G][DEG], rely[G][DEG];
    __shared__ int   npd[G][DEG];
    __shared__ int   klist[G][MAXO];
    __shared__ int   kcnt[G];
    __shared__ float kc[G][MAXO][20];              // kept rows (<=15), 10.2 KB
    __shared__ float Hs[EMBED][G];
    __shared__ float Mg[EMBED][G];
    __shared__ float lg[G][MAXO + 1];
    __shared__ int   n2s[G];
    __shared__ int   wcnt[4];

    // --- per-(agent,neighbor) metadata ---
    if (tid < G * DEG) {
        const int g = tid >> 3, d = tid & 7;
        const int e = (i0 + g) * DEG + d;
        const int j  = comm_edge[e];
        const int ii = comm_edge[A_N * DEG + e];
        jn[g][d]  = j;
        relx[g][d] = agent_pos[j * 2 + 0] - agent_pos[ii * 2 + 0];
        rely[g][d] = agent_pos[j * 2 + 1] - agent_pos[ii * 2 + 1];
        npd[g][d] = npred[j];
    }
    __syncthreads();

    // --- positions + valid for all 1024 candidates ---
    for (int idx = tid; idx < G * KCAND; idx += NTHR) {
        const int g = idx >> 7, k = idx & 127, d = k >> 4, m = k & 15;
        const float* eb = elems_base + (size_t)jn[g][d] * (MAXO * ORIG) + m * ORIG;
        float2 p = *(const float2*)(eb + 16);
        p.x += relx[g][d]; p.y += rely[g][d];
        pxy[g][k] = p;
        vldA[g][k] = (m < npd[g][d]) ? 1 : 0;
    }
    __syncthreads();

    // --- dedup + cap(15) + compact kept list: 4 rounds x 2 agents ---
    for (int r = 0; r < 4; ++r) {
        const int g = r * 2 + half;
        const int k = col;
        const float2 my = pxy[g][k];
        int dup = 0;
        for (int k1 = 0; k1 < KCAND; ++k1) {
            if (vldA[g][k1]) {                      // wave-uniform branch
                const float2 p1 = pxy[g][k1];
                const float dx = p1.x - my.x, dy = p1.y - my.y;
                if (k1 < k && sqrtf(dx * dx + dy * dy) < 0.02f) dup = 1;
            }
        }
        int kp = (vldA[g][k] && !dup) ? 1 : 0;
        const unsigned long long bal = __ballot(kp);
        const int lane = tid & 63, w = tid >> 6;
        int cnt = (int)__popcll(bal << (63 - lane));    // inclusive in-wave prefix
        if (lane == 63) wcnt[w] = (int)__popcll(bal);
        __syncthreads();
        if (w & 1) cnt += wcnt[w - 1];                  // carry from even wave
        if (k == 127) kcnt[g] = (cnt < MAXO - 1) ? cnt : (MAXO - 1);
        if (kp && cnt <= MAXO - 1) klist[g][cnt - 1] = k;
        __syncthreads();
    }

    // --- gather kept candidate features (<=15*18 per agent) ---
    for (int idx = tid; idx < G * MAXO * ORIG; idx += NTHR) {
        const int g = idx / (MAXO * ORIG), rem = idx % (MAXO * ORIG);
        const int s = rem / ORIG, c = rem % ORIG;
        if (s < kcnt[g]) {
            const int k = klist[g][s], d = k >> 4, m = k & 15;
            float v;
            if (c < 16) v = elems_base[(size_t)jn[g][d] * (MAXO * ORIG) + m * ORIG + c];
            else        v = (c == 16) ? pxy[g][k].x : pxy[g][k].y;
            kc[g][s][c] = v;
        }
    }
    __syncthreads();

    // --- hsum[col][g] = sum over kept rows of relu(row . W1col + b1) ---
    {
        float w1[ORIG];
#pragma unroll
        for (int c = 0; c < ORIG; ++c) w1[c] = menc_W1[c * EMBED + col];
        const float b1 = menc_b1[col];
        for (int gg = 0; gg < 4; ++gg) {
            const int g = 4 * half + gg;
            const int nk = kcnt[g];
            float hs = 0.f;
            for (int s = 0; s < nk; ++s) {
                const float4* mr = (const float4*)&kc[g][s][0];
                const float4 m0 = mr[0], m1 = mr[1], m2 = mr[2], m3 = mr[3];
                const float2 m4 = *(const float2*)&kc[g][s][16];
                float h = b1
                    + m0.x*w1[0]  + m0.y*w1[1]  + m0.z*w1[2]  + m0.w*w1[3]
                    + m1.x*w1[4]  + m1.y*w1[5]  + m1.z*w1[6]  + m1.w*w1[7]
                    + m2.x*w1[8]  + m2.y*w1[9]  + m2.z*w1[10] + m2.w*w1[11]
                    + m3.x*w1[12] + m3.y*w1[13] + m3.z*w1[14] + m3.w*w1[15]
                    + m4.x*w1[16] + m4.y*w1[17];
                hs += fmaxf(h, 0.f);
            }
            Hs[col][g] = hs;
        }
    }
    __syncthreads();

    // --- merged = hsum@W2 + b2 ---
    {
        const float b2 = menc_b2[col];
        float e0 = b2, e1 = b2, e2 = b2, e3 = b2;
        for (int c = 0; c < EMBED; ++c) {
            const float4 s = *(const float4*)&Hs[c][4 * half];
            const float  w = menc_W2[c * EMBED + col];
            e0 += s.x * w; e1 += s.y * w; e2 += s.z * w; e3 += s.w * w;
        }
        Mg[col][4 * half + 0] = e0; Mg[col][4 * half + 1] = e1;
        Mg[col][4 * half + 2] = e2; Mg[col][4 * half + 3] = e3;
    }
    __syncthreads();

    // --- n2 = argmax(merged@Ws + bs) ---
    if (tid < G * (MAXO + 1)) {
        const int g = tid / (MAXO + 1), q = tid % (MAXO + 1);
        float v = dec_bs[q];
        for (int c = 0; c < EMBED; ++c) v += Mg[c][g] * dec_Ws[c * (MAXO + 1) + q];
        lg[g][q] = v;
    }
    __syncthreads();
    if (tid < G) {
        int best = 0; float bv = lg[tid][0];
        for (int q = 1; q <= MAXO; ++q) if (lg[tid][q] > bv) { bv = lg[tid][q]; best = q; }
        n2s[tid] = best;
    }
    __syncthreads();

    // --- decoded (masked) + batch + mask ---
    for (int e = col; e < MAXO * ORIG; e += 128) {
        const int m = e / ORIG;
        const float bx = dec_bx[e];
        float a0 = bx, a1 = bx, a2 = bx, a3 = bx;
        for (int c = 0; c < EMBED; ++c) {
            const float4 s = *(const float4*)&Mg[c][4 * half];
            const float  w = dec_Wx[c * (MAXO * ORIG) + e];
            a0 += s.x * w; a1 += s.y * w; a2 += s.z * w; a3 += s.w * w;
        }
        const int g0 = 4 * half;
        out_dec[(size_t)(i0 + g0 + 0) * (MAXO * ORIG) + e] = (m < n2s[g0 + 0]) ? a0 : 0.f;
        out_dec[(size_t)(i0 + g0 + 1) * (MAXO * ORIG) + e] = (m < n2s[g0 + 1]) ? a1 : 0.f;
        out_dec[(size_t)(i0 + g0 + 2) * (MAXO * ORIG) + e] = (m < n2s[g0 + 2]) ? a2 : 0.f;
        out_dec[(size_t)(i0 + g0 + 3) * (MAXO * ORIG) + e] = (m < n2s[g0 + 3]) ? a3 : 0.f;
    }
    if (tid < G * MAXO) {
        const int g = tid >> 4, m = tid & 15;
        out_batch[(i0 + g) * MAXO + m] = (float)(i0 + g);
        out_mask[(i0 + g) * MAXO + m]  = (m < n2s[g]) ? 1.f : 0.f;
    }
}

extern "C" void kernel_launch(void* const* d_in, const int* in_sizes, int n_in,
                              void* d_out, int out_size, void* d_ws, size_t ws_size,
                              hipStream_t stream)
{
    const float* obj_x     = (const float*)d_in[0];
    const float* obj_pos   = (const float*)d_in[1];
    const float* agent_pos = (const float*)d_in[2];
    const float* enc_W1    = (const float*)d_in[3];
    const float* enc_b1    = (const float*)d_in[4];
    const float* enc_W2    = (const float*)d_in[5];
    const float* enc_b2    = (const float*)d_in[6];
    const float* mdec_Ws   = (const float*)d_in[7];
    const float* mdec_bs   = (const float*)d_in[8];
    const float* mdec_Wx   = (const float*)d_in[9];
    const float* mdec_bx   = (const float*)d_in[10];
    const float* menc_W1   = (const float*)d_in[11];
    const float* menc_b1   = (const float*)d_in[12];
    const float* menc_W2   = (const float*)d_in[13];
    const float* menc_b2   = (const float*)d_in[14];
    const float* dec_Ws    = (const float*)d_in[15];
    const float* dec_bs    = (const float*)d_in[16];
    const float* dec_Wx    = (const float*)d_in[17];
    const float* dec_bx    = (const float*)d_in[18];
    const int*   obs_edge  = (const int*)d_in[19];
    const int*   comm_edge = (const int*)d_in[20];

    float* elems_base = (float*)d_ws;                                  // 4096*288 f32
    int*   npred      = (int*)((char*)d_ws + (size_t)A_N * MAXO * ORIG * sizeof(float));

    float* out_dec   = (float*)d_out;
    float* out_batch = out_dec + (size_t)A_N * MAXO * ORIG;
    float* out_mask  = out_batch + (size_t)A_N * MAXO;

    enc8_kernel<<<NBLK, NTHR, 0, stream>>>(
        obj_x, obj_pos, agent_pos, enc_W1, enc_b1, enc_W2, enc_b2,
        mdec_Ws, mdec_bs, mdec_Wx, mdec_bx, obs_edge, elems_base, npred);

    merge8_kernel<<<NBLK, NTHR, 0, stream>>>(
        agent_pos, menc_W1, menc_b1, menc_W2, menc_b2,
        dec_Ws, dec_bs, dec_Wx, dec_bx, comm_edge,
        elems_base, npred, out_dec, out_batch, out_mask);
}

// Round 4
// 176.669 us; speedup vs baseline: 1.2844x; 1.2844x over previous
//
#include <hip/hip_runtime.h>

#define A_N   4096
#define EMBED 128
#define MAXO  16
#define DEG   8
#define OBSD  8
#define ORIG  18
#define KCAND 128          // DEG*MAXO candidates per agent
#define G     4            // agents per block (one wave per agent in merge)
#define NBLK  (A_N / G)    // 1024 blocks -> 4 blocks/CU, 16 waves/CU
#define NTHR  256

// ---------------------------------------------------------------------------
// Kernel A: 4 source agents per block.
// Phases: msg gather -> relu(msg@W1+b1) segsum -> S ; enc=S@W2+b2 (split-K);
// npred=argmax(enc@Ws+bs); elems_base=enc@Wx+bx.
// Activations live in LDS as float4[c] = 4 agents -> 4 FMA per b128 read.
// ---------------------------------------------------------------------------
__global__ __launch_bounds__(NTHR) void enc4_kernel(
    const float* __restrict__ obj_x, const float* __restrict__ obj_pos,
    const float* __restrict__ agent_pos,
    const float* __restrict__ enc_W1, const float* __restrict__ enc_b1,
    const float* __restrict__ enc_W2, const float* __restrict__ enc_b2,
    const float* __restrict__ mdec_Ws, const float* __restrict__ mdec_bs,
    const float* __restrict__ mdec_Wx, const float* __restrict__ mdec_bx,
    const int* __restrict__ obs_edge,
    float* __restrict__ elems_base, int* __restrict__ npred_out)
{
    const int blk = blockIdx.x, tid = threadIdx.x;
    const int i0  = blk * G;
    const int col = tid & 127, pair = tid >> 7;

    __shared__ int    on[G][OBSD];
    __shared__ float  msg[G * OBSD][20];     // 32 rows x 18 (pad 20)
    __shared__ float4 SG[EMBED];             // [c] -> 4 agents
    __shared__ float4 Ep[2][EMBED];          // split-K partials
    __shared__ float4 Eg[EMBED];             // enc, [c] -> 4 agents
    __shared__ float  lgts[G][MAXO + 1];

    if (tid < G * OBSD) {
        const int g = tid >> 3, d = tid & 7;
        on[g][d] = obs_edge[A_N * OBSD + (i0 + g) * OBSD + d];
    }
    __syncthreads();
    for (int idx = tid; idx < G * OBSD * ORIG; idx += NTHR) {
        const int r = idx / ORIG, c = idx % ORIG;
        const int g = r >> 3, d = r & 7;
        const int o = on[g][d];
        float v;
        if (c < 16) v = obj_x[o * 16 + c];
        else        v = obj_pos[o * 2 + (c - 16)] - agent_pos[(i0 + g) * 2 + (c - 16)];
        msg[r][c] = v;
    }
    __syncthreads();

    // --- relu(msg@W1+b1), segment-sum: thread (col,pair) does agents 2p,2p+1
    {
        float w1[ORIG];
#pragma unroll
        for (int c = 0; c < ORIG; ++c) w1[c] = enc_W1[c * EMBED + col];
        const float b1 = enc_b1[col];
#pragma unroll
        for (int gg = 0; gg < 2; ++gg) {
            const int g = 2 * pair + gg;
            float acc = 0.f;
#pragma unroll
            for (int d = 0; d < OBSD; ++d) {
                const int r = g * OBSD + d;
                const float4* mr = (const float4*)&msg[r][0];
                const float4 m0 = mr[0], m1 = mr[1], m2 = mr[2], m3 = mr[3];
                const float2 m4 = *(const float2*)&msg[r][16];
                float h = b1
                    + m0.x*w1[0]  + m0.y*w1[1]  + m0.z*w1[2]  + m0.w*w1[3]
                    + m1.x*w1[4]  + m1.y*w1[5]  + m1.z*w1[6]  + m1.w*w1[7]
                    + m2.x*w1[8]  + m2.y*w1[9]  + m2.z*w1[10] + m2.w*w1[11]
                    + m3.x*w1[12] + m3.y*w1[13] + m3.z*w1[14] + m3.w*w1[15]
                    + m4.x*w1[16] + m4.y*w1[17];
                acc += fmaxf(h, 0.f);
            }
            ((float*)&SG[col])[g] = acc;
        }
    }
    __syncthreads();

    // --- enc = S@W2 + b2, split-K (pair = K-half) ---
    {
        float4 acc = {0.f, 0.f, 0.f, 0.f};
        const int c0 = 64 * pair;
#pragma unroll 8
        for (int c = c0; c < c0 + 64; ++c) {
            const float4 s = SG[c];
            const float  w = enc_W2[c * EMBED + col];
            acc.x += s.x * w; acc.y += s.y * w; acc.z += s.z * w; acc.w += s.w * w;
        }
        Ep[pair][col] = acc;
    }
    __syncthreads();
    if (tid < EMBED) {
        const float4 a = Ep[0][tid], b = Ep[1][tid];
        const float bb = enc_b2[tid];
        float4 e;
        e.x = a.x + b.x + bb; e.y = a.y + b.y + bb;
        e.z = a.z + b.z + bb; e.w = a.w + b.w + bb;
        Eg[tid] = e;
    }
    __syncthreads();

    // --- npred = argmax(enc@Ws + bs) ---
    if (tid < G * (MAXO + 1)) {
        const int g = tid / (MAXO + 1), q = tid % (MAXO + 1);
        float v = mdec_bs[q];
        for (int c = 0; c < EMBED; ++c)
            v += ((const float*)&Eg[c])[g] * mdec_Ws[c * (MAXO + 1) + q];
        lgts[g][q] = v;
    }
    __syncthreads();
    if (tid < G) {
        int best = 0; float bv = lgts[tid][0];
        for (int q = 1; q <= MAXO; ++q) if (lgts[tid][q] > bv) { bv = lgts[tid][q]; best = q; }
        npred_out[i0 + tid] = best;
    }

    // --- elems_base = enc@Wx + bx (288 outputs, 4 agents per thread) ---
    for (int e = tid; e < MAXO * ORIG; e += NTHR) {
        const float bx = mdec_bx[e];
        float4 acc = {bx, bx, bx, bx};
#pragma unroll 8
        for (int c = 0; c < EMBED; ++c) {
            const float4 s = Eg[c];
            const float  w = mdec_Wx[c * (MAXO * ORIG) + e];
            acc.x += s.x * w; acc.y += s.y * w; acc.z += s.z * w; acc.w += s.w * w;
        }
        elems_base[(size_t)(i0 + 0) * (MAXO * ORIG) + e] = acc.x;
        elems_base[(size_t)(i0 + 1) * (MAXO * ORIG) + e] = acc.y;
        elems_base[(size_t)(i0 + 2) * (MAXO * ORIG) + e] = acc.z;
        elems_base[(size_t)(i0 + 3) * (MAXO * ORIG) + e] = acc.w;
    }
}

// ---------------------------------------------------------------------------
// Kernel B: 4 target agents per block, one WAVE per agent for dedup phases.
// pxy/valid -> compact valid list -> dedup vs earlier-valid (ascending scan,
// early exit) -> cap 15 -> gather kept rows -> hsum -> merged (split-K) ->
// heads -> masked decode.
// ---------------------------------------------------------------------------
__global__ __launch_bounds__(NTHR) void merge4_kernel(
    const float* __restrict__ agent_pos,
    const float* __restrict__ menc_W1, const float* __restrict__ menc_b1,
    const float* __restrict__ menc_W2, const float* __restrict__ menc_b2,
    const float* __restrict__ dec_Ws, const float* __restrict__ dec_bs,
    const float* __restrict__ dec_Wx, const float* __restrict__ dec_bx,
    const int* __restrict__ comm_edge,
    const float* __restrict__ elems_base, const int* __restrict__ npred,
    float* __restrict__ out_dec, float* __restrict__ out_batch,
    float* __restrict__ out_mask)
{
    const int blk = blockIdx.x, tid = threadIdx.x;
    const int i0  = blk * G;
    const int col = tid & 127, pair = tid >> 7;
    const int lane = tid & 63, wv = tid >> 6;    // wave wv handles agent g=wv

    __shared__ int    jn[G][DEG];
    __shared__ float  relx[G][DEG], rely[G][DEG];
    __shared__ int    npd[G][DEG];
    __shared__ float2 pxy[G][KCAND];
    __shared__ int    vl[G][KCAND];      // ascending compacted valid list
    __shared__ int    nvp[G], nv[G];
    __shared__ int    kpp[G], kcnt[G];
    __shared__ int    klist[G][MAXO];
    __shared__ float  kc[G][MAXO][20];
    __shared__ float4 Hs[EMBED];
    __shared__ float4 Mp[2][EMBED];
    __shared__ float4 Mg[EMBED];
    __shared__ float  lg2[G][MAXO + 1];
    __shared__ int    n2s[G];

    if (tid < G * DEG) {
        const int g = tid >> 3, d = tid & 7;
        const int e = (i0 + g) * DEG + d;
        const int j  = comm_edge[e];
        const int ii = comm_edge[A_N * DEG + e];
        jn[g][d]  = j;
        relx[g][d] = agent_pos[j * 2 + 0] - agent_pos[ii * 2 + 0];
        rely[g][d] = agent_pos[j * 2 + 1] - agent_pos[ii * 2 + 1];
        npd[g][d] = npred[j];
    }
    __syncthreads();

    // --- positions + compacted valid list (wave g, rounds r=0,1 cover 128 k) ---
    for (int r = 0; r < 2; ++r) {
        const int k = 64 * r + lane;
        const int d = k >> 4, m = k & 15;
        const float* eb = elems_base + (size_t)jn[wv][d] * (MAXO * ORIG) + m * ORIG;
        float2 p = *(const float2*)(eb + 16);
        p.x += relx[wv][d]; p.y += rely[wv][d];
        pxy[wv][k] = p;
        const int val = (m < npd[wv][d]) ? 1 : 0;
        const unsigned long long bal = __ballot(val);
        const int pref = (int)__popcll(bal << (63 - lane));
        const int base = (r == 0) ? 0 : nvp[wv];
        if (val) vl[wv][base + pref - 1] = k;
        if (lane == 63) {
            if (r == 0) nvp[wv] = (int)__popcll(bal);
            else        nv[wv]  = nvp[wv] + (int)__popcll(bal);
        }
    }
    // same-wave LDS ordering: no block barrier needed between rounds

    // --- dedup + cap 15 (wave g): scan earlier valid candidates only ---
    for (int r = 0; r < 2; ++r) {
        const int k = 64 * r + lane;
        const float2 my = pxy[wv][k];
        const int nvg = nv[wv];
        int dup = 0;
        for (int idx = 0; idx < nvg; ++idx) {
            const int k1 = vl[wv][idx];
            if (k1 >= k) break;                       // list ascending
            const float2 p1 = pxy[wv][k1];
            const float dx = p1.x - my.x, dy = p1.y - my.y;
            if (sqrtf(dx * dx + dy * dy) < 0.02f) dup = 1;
        }
        const int val = ((k & 15) < npd[wv][k >> 4]) ? 1 : 0;
        const int kp = (val && !dup) ? 1 : 0;
        const unsigned long long bal = __ballot(kp);
        const int pref = (int)__popcll(bal << (63 - lane));
        const int base = (r == 0) ? 0 : kpp[wv];
        const int cnt = base + pref;
        if (kp && cnt <= MAXO - 1) klist[wv][cnt - 1] = k;
        if (lane == 63) {
            if (r == 0) kpp[wv] = (int)__popcll(bal);
            else {
                int tot = kpp[wv] + (int)__popcll(bal);
                kcnt[wv] = (tot < MAXO - 1) ? tot : (MAXO - 1);
            }
        }
    }
    __syncthreads();

    // --- gather kept rows ---
    for (int idx = tid; idx < G * MAXO * ORIG; idx += NTHR) {
        const int g = idx / (MAXO * ORIG), rem = idx % (MAXO * ORIG);
        const int s = rem / ORIG, c = rem % ORIG;
        if (s < kcnt[g]) {
            const int k = klist[g][s], d = k >> 4, m = k & 15;
            float v;
            if (c < 16) v = elems_base[(size_t)jn[g][d] * (MAXO * ORIG) + m * ORIG + c];
            else        v = (c == 16) ? pxy[g][k].x : pxy[g][k].y;
            kc[g][s][c] = v;
        }
    }
    __syncthreads();

    // --- hsum: thread (col,pair) does agents 2p,2p+1 over <=15 kept rows ---
    {
        float w1[ORIG];
#pragma unroll
        for (int c = 0; c < ORIG; ++c) w1[c] = menc_W1[c * EMBED + col];
        const float b1 = menc_b1[col];
#pragma unroll
        for (int gg = 0; gg < 2; ++gg) {
            const int g = 2 * pair + gg;
            const int nk = kcnt[g];
            float hs = 0.f;
            for (int s = 0; s < nk; ++s) {
                const float4* mr = (const float4*)&kc[g][s][0];
                const float4 m0 = mr[0], m1 = mr[1], m2 = mr[2], m3 = mr[3];
                const float2 m4 = *(const float2*)&kc[g][s][16];
                float h = b1
                    + m0.x*w1[0]  + m0.y*w1[1]  + m0.z*w1[2]  + m0.w*w1[3]
                    + m1.x*w1[4]  + m1.y*w1[5]  + m1.z*w1[6]  + m1.w*w1[7]
                    + m2.x*w1[8]  + m2.y*w1[9]  + m2.z*w1[10] + m2.w*w1[11]
                    + m3.x*w1[12] + m3.y*w1[13] + m3.z*w1[14] + m3.w*w1[15]
                    + m4.x*w1[16] + m4.y*w1[17];
                hs += fmaxf(h, 0.f);
            }
            ((float*)&Hs[col])[g] = hs;
        }
    }
    __syncthreads();

    // --- merged = hsum@W2 + b2, split-K ---
    {
        float4 acc = {0.f, 0.f, 0.f, 0.f};
        const int c0 = 64 * pair;
#pragma unroll 8
        for (int c = c0; c < c0 + 64; ++c) {
            const float4 s = Hs[c];
            const float  w = menc_W2[c * EMBED + col];
            acc.x += s.x * w; acc.y += s.y * w; acc.z += s.z * w; acc.w += s.w * w;
        }
        Mp[pair][col] = acc;
    }
    __syncthreads();
    if (tid < EMBED) {
        const float4 a = Mp[0][tid], b = Mp[1][tid];
        const float bb = menc_b2[tid];
        float4 e;
        e.x = a.x + b.x + bb; e.y = a.y + b.y + bb;
        e.z = a.z + b.z + bb; e.w = a.w + b.w + bb;
        Mg[tid] = e;
    }
    __syncthreads();

    // --- n2 = argmax(merged@Ws + bs) ---
    if (tid < G * (MAXO + 1)) {
        const int g = tid / (MAXO + 1), q = tid % (MAXO + 1);
        float v = dec_bs[q];
        for (int c = 0; c < EMBED; ++c)
            v += ((const float*)&Mg[c])[g] * dec_Ws[c * (MAXO + 1) + q];
        lg2[g][q] = v;
    }
    __syncthreads();
    if (tid < G) {
        int best = 0; float bv = lg2[tid][0];
        for (int q = 1; q <= MAXO; ++q) if (lg2[tid][q] > bv) { bv = lg2[tid][q]; best = q; }
        n2s[tid] = best;
    }
    __syncthreads();

    // --- masked decode + batch + mask ---
    for (int e = tid; e < MAXO * ORIG; e += NTHR) {
        const int m = e / ORIG;
        const float bx = dec_bx[e];
        float4 acc = {bx, bx, bx, bx};
#pragma unroll 8
        for (int c = 0; c < EMBED; ++c) {
            const float4 s = Mg[c];
            const float  w = dec_Wx[c * (MAXO * ORIG) + e];
            acc.x += s.x * w; acc.y += s.y * w; acc.z += s.z * w; acc.w += s.w * w;
        }
        out_dec[(size_t)(i0 + 0) * (MAXO * ORIG) + e] = (m < n2s[0]) ? acc.x : 0.f;
        out_dec[(size_t)(i0 + 1) * (MAXO * ORIG) + e] = (m < n2s[1]) ? acc.y : 0.f;
        out_dec[(size_t)(i0 + 2) * (MAXO * ORIG) + e] = (m < n2s[2]) ? acc.z : 0.f;
        out_dec[(size_t)(i0 + 3) * (MAXO * ORIG) + e] = (m < n2s[3]) ? acc.w : 0.f;
    }
    if (tid < G * MAXO) {
        const int g = tid >> 4, m = tid & 15;
        out_batch[(i0 + g) * MAXO + m] = (float)(i0 + g);
        out_mask[(i0 + g) * MAXO + m]  = (m < n2s[g]) ? 1.f : 0.f;
    }
}

extern "C" void kernel_launch(void* const* d_in, const int* in_sizes, int n_in,
                              void* d_out, int out_size, void* d_ws, size_t ws_size,
                              hipStream_t stream)
{
    const float* obj_x     = (const float*)d_in[0];
    const float* obj_pos   = (const float*)d_in[1];
    const float* agent_pos = (const float*)d_in[2];
    const float* enc_W1    = (const float*)d_in[3];
    const float* enc_b1    = (const float*)d_in[4];
    const float* enc_W2    = (const float*)d_in[5];
    const float* enc_b2    = (const float*)d_in[6];
    const float* mdec_Ws   = (const float*)d_in[7];
    const float* mdec_bs   = (const float*)d_in[8];
    const float* mdec_Wx   = (const float*)d_in[9];
    const float* mdec_bx   = (const float*)d_in[10];
    const float* menc_W1   = (const float*)d_in[11];
    const float* menc_b1   = (const float*)d_in[12];
    const float* menc_W2   = (const float*)d_in[13];
    const float* menc_b2   = (const float*)d_in[14];
    const float* dec_Ws    = (const float*)d_in[15];
    const float* dec_bs    = (const float*)d_in[16];
    const float* dec_Wx    = (const float*)d_in[17];
    const float* dec_bx    = (const float*)d_in[18];
    const int*   obs_edge  = (const int*)d_in[19];
    const int*   comm_edge = (const int*)d_in[20];

    float* elems_base = (float*)d_ws;                                  // 4096*288 f32
    int*   npred      = (int*)((char*)d_ws + (size_t)A_N * MAXO * ORIG * sizeof(float));

    float* out_dec   = (float*)d_out;
    float* out_batch = out_dec + (size_t)A_N * MAXO * ORIG;
    float* out_mask  = out_batch + (size_t)A_N * MAXO;

    enc4_kernel<<<NBLK, NTHR, 0, stream>>>(
        obj_x, obj_pos, agent_pos, enc_W1, enc_b1, enc_W2, enc_b2,
        mdec_Ws, mdec_bs, mdec_Wx, mdec_bx, obs_edge, elems_base, npred);

    merge4_kernel<<<NBLK, NTHR, 0, stream>>>(
        agent_pos, menc_W1, menc_b1, menc_W2, menc_b2,
        dec_Ws, dec_bs, dec_Wx, dec_bx, comm_edge,
        elems_base, npred, out_dec, out_batch, out_mask);
}

// Round 6
// 163.856 us; speedup vs baseline: 1.3848x; 1.0782x over previous
//
#include <hip/hip_runtime.h>

#define A_N   4096
#define EMBED 128
#define MAXO  16
#define DEG   8
#define OBSD  8
#define ORIG  18
#define KCAND 128            // DEG*MAXO candidates per agent
#define G     4              // agents per block
#define NBLK  (A_N / G)      // 1024 blocks
#define NTHR  512            // 8 waves/block -> 4 blocks/CU = 32 waves/CU
#define EL    (MAXO * ORIG)  // 288

// ---------------------------------------------------------------------------
// Kernel A: 4 source agents, 512 threads.
// thread (col=tid&127, q=tid>>7): agent q for row phases; split-K4 on W2;
// split-K2 (576 units) on the 288-wide elems GEMV.
// ---------------------------------------------------------------------------
__global__ __launch_bounds__(NTHR, 8) void enc512_kernel(
    const float* __restrict__ obj_x, const float* __restrict__ obj_pos,
    const float* __restrict__ agent_pos,
    const float* __restrict__ enc_W1, const float* __restrict__ enc_b1,
    const float* __restrict__ enc_W2, const float* __restrict__ enc_b2,
    const float* __restrict__ mdec_Ws, const float* __restrict__ mdec_bs,
    const float* __restrict__ mdec_Wx, const float* __restrict__ mdec_bx,
    const int* __restrict__ obs_edge,
    float* __restrict__ elems_base, int* __restrict__ npred_out)
{
    const int blk = blockIdx.x, tid = threadIdx.x;
    const int i0  = blk * G;
    const int col = tid & 127, q = tid >> 7;

    __shared__ int    on[G][OBSD];
    __shared__ float  msg[G * OBSD][20];
    __shared__ float4 SG[EMBED];          // [c] -> 4 agents
    __shared__ float4 Ep4[4][EMBED];      // split-K4 partials
    __shared__ float4 Eg[EMBED];
    __shared__ float  lgts[G][MAXO + 1];
    __shared__ float4 Pp[2][EL];          // split-K2 partials for elems

    if (tid < G * OBSD) {
        const int g = tid >> 3, d = tid & 7;
        on[g][d] = obs_edge[A_N * OBSD + (i0 + g) * OBSD + d];
    }
    __syncthreads();
    for (int idx = tid; idx < G * OBSD * ORIG; idx += NTHR) {
        const int r = idx / ORIG, c = idx % ORIG;
        const int g = r >> 3, d = r & 7;
        const int o = on[g][d];
        float v;
        if (c < 16) v = obj_x[o * 16 + c];
        else        v = obj_pos[o * 2 + (c - 16)] - agent_pos[(i0 + g) * 2 + (c - 16)];
        msg[r][c] = v;
    }
    __syncthreads();

    // --- h = relu(msg@W1+b1), segment-sum; thread (col,q) -> agent q ---
    {
        float w1[ORIG];
#pragma unroll
        for (int c = 0; c < ORIG; ++c) w1[c] = enc_W1[c * EMBED + col];
        const float b1 = enc_b1[col];
        float acc = 0.f;
#pragma unroll
        for (int d = 0; d < OBSD; ++d) {
            const int r = q * OBSD + d;
            const float4* mr = (const float4*)&msg[r][0];
            const float4 m0 = mr[0], m1 = mr[1], m2 = mr[2], m3 = mr[3];
            const float2 m4 = *(const float2*)&msg[r][16];
            float h = b1
                + m0.x*w1[0]  + m0.y*w1[1]  + m0.z*w1[2]  + m0.w*w1[3]
                + m1.x*w1[4]  + m1.y*w1[5]  + m1.z*w1[6]  + m1.w*w1[7]
                + m2.x*w1[8]  + m2.y*w1[9]  + m2.z*w1[10] + m2.w*w1[11]
                + m3.x*w1[12] + m3.y*w1[13] + m3.z*w1[14] + m3.w*w1[15]
                + m4.x*w1[16] + m4.y*w1[17];
            acc += fmaxf(h, 0.f);
        }
        ((float*)&SG[col])[q] = acc;
    }
    __syncthreads();

    // --- enc = S@W2 + b2, split-K4 ---
    {
        float4 acc = {0.f, 0.f, 0.f, 0.f};
        const int c0 = 32 * q;
#pragma unroll 8
        for (int c = c0; c < c0 + 32; ++c) {
            const float4 s = SG[c];
            const float  w = enc_W2[c * EMBED + col];
            acc.x += s.x * w; acc.y += s.y * w; acc.z += s.z * w; acc.w += s.w * w;
        }
        Ep4[q][col] = acc;
    }
    __syncthreads();
    if (tid < EMBED) {
        const float4 a = Ep4[0][tid], b = Ep4[1][tid], c = Ep4[2][tid], d = Ep4[3][tid];
        const float bb = enc_b2[tid];
        float4 e;
        e.x = a.x + b.x + c.x + d.x + bb;
        e.y = a.y + b.y + c.y + d.y + bb;
        e.z = a.z + b.z + c.z + d.z + bb;
        e.w = a.w + b.w + c.w + d.w + bb;
        Eg[tid] = e;
    }
    __syncthreads();

    // --- npred = argmax(enc@Ws + bs) ---
    if (tid < G * (MAXO + 1)) {
        const int g = tid / (MAXO + 1), qq = tid % (MAXO + 1);
        float v = mdec_bs[qq];
        for (int c = 0; c < EMBED; ++c)
            v += ((const float*)&Eg[c])[g] * mdec_Ws[c * (MAXO + 1) + qq];
        lgts[g][qq] = v;
    }
    __syncthreads();
    if (tid < G) {
        int best = 0; float bv = lgts[tid][0];
        for (int qq = 1; qq <= MAXO; ++qq) if (lgts[tid][qq] > bv) { bv = lgts[tid][qq]; best = qq; }
        npred_out[i0 + tid] = best;
    }

    // --- elems = enc@Wx + bx, split-K2: 576 units over 512 threads ---
    {
        int u = tid;
        for (int pass = 0; pass < 2; ++pass) {
            if (u < 2 * EL) {
                const int h = (u >= EL) ? 1 : 0;
                const int e = u - h * EL;
                float4 acc = {0.f, 0.f, 0.f, 0.f};
                const int c0 = 64 * h;
#pragma unroll 8
                for (int c = c0; c < c0 + 64; ++c) {
                    const float4 s = Eg[c];
                    const float  w = mdec_Wx[c * EL + e];
                    acc.x += s.x * w; acc.y += s.y * w; acc.z += s.z * w; acc.w += s.w * w;
                }
                Pp[h][e] = acc;
            }
            u = NTHR + tid;      // second pass covers units 512..575 (tid<64)
        }
    }
    __syncthreads();
    if (tid < EL) {
        const float4 a = Pp[0][tid], b = Pp[1][tid];
        const float bx = mdec_bx[tid];
        elems_base[(size_t)(i0 + 0) * EL + tid] = a.x + b.x + bx;
        elems_base[(size_t)(i0 + 1) * EL + tid] = a.y + b.y + bx;
        elems_base[(size_t)(i0 + 2) * EL + tid] = a.z + b.z + bx;
        elems_base[(size_t)(i0 + 3) * EL + tid] = a.w + b.w + bx;
    }
}

// ---------------------------------------------------------------------------
// Kernel B: 4 target agents, 512 threads = 8 waves; wave-pair (w=wv>>1,
// half=wv&1) handles agent w's candidate half-tile for dedup phases.
// ---------------------------------------------------------------------------
__global__ __launch_bounds__(NTHR, 8) void merge512_kernel(
    const float* __restrict__ agent_pos,
    const float* __restrict__ menc_W1, const float* __restrict__ menc_b1,
    const float* __restrict__ menc_W2, const float* __restrict__ menc_b2,
    const float* __restrict__ dec_Ws, const float* __restrict__ dec_bs,
    const float* __restrict__ dec_Wx, const float* __restrict__ dec_bx,
    const int* __restrict__ comm_edge,
    const float* __restrict__ elems_base, const int* __restrict__ npred,
    float* __restrict__ out_dec, float* __restrict__ out_batch,
    float* __restrict__ out_mask)
{
    const int blk = blockIdx.x, tid = threadIdx.x;
    const int i0  = blk * G;
    const int col = tid & 127, q = tid >> 7;
    const int lane = tid & 63, wv = tid >> 6;
    const int w = wv >> 1, half = wv & 1;

    __shared__ int    jn[G][DEG];
    __shared__ float  relx[G][DEG], rely[G][DEG];
    __shared__ int    npd[G][DEG];
    __shared__ float2 pxy[G][KCAND];
    __shared__ int    vl[G][KCAND];
    __shared__ int    wcv[G][2], kcv[G][2];
    __shared__ int    nv[G], kcnt[G];
    __shared__ int    klist[G][MAXO];
    __shared__ float  kc[G][MAXO][20];
    __shared__ float4 Hs[EMBED];
    __shared__ float4 Mp4[4][EMBED];
    __shared__ float4 Mg[EMBED];
    __shared__ float  lg2[G][MAXO + 1];
    __shared__ int    n2s[G];
    __shared__ float4 Pp[2][EL];

    if (tid < G * DEG) {
        const int g = tid >> 3, d = tid & 7;
        const int e = (i0 + g) * DEG + d;
        const int j  = comm_edge[e];
        const int ii = comm_edge[A_N * DEG + e];
        jn[g][d]  = j;
        relx[g][d] = agent_pos[j * 2 + 0] - agent_pos[ii * 2 + 0];
        rely[g][d] = agent_pos[j * 2 + 1] - agent_pos[ii * 2 + 1];
        npd[g][d] = npred[j];
    }
    __syncthreads();

    // --- positions + valid, compacted valid list (wave-pair per agent) ---
    const int k = 64 * half + lane;
    const int kd = k >> 4, km = k & 15;
    {
        const float* eb = elems_base + (size_t)jn[w][kd] * EL + km * ORIG;
        float2 p = *(const float2*)(eb + 16);
        p.x += relx[w][kd]; p.y += rely[w][kd];
        pxy[w][k] = p;
        const int val = (km < npd[w][kd]) ? 1 : 0;
        const unsigned long long bal = __ballot(val);
        const int pref = (int)__popcll(bal << (63 - lane));
        if (lane == 63) wcv[w][half] = (int)__popcll(bal);
        __syncthreads();
        const int base = half ? wcv[w][0] : 0;
        if (val) vl[w][base + pref - 1] = k;
        if (lane == 0 && half == 0) nv[w] = wcv[w][0] + wcv[w][1];
        __syncthreads();
    }

    // --- dedup + cap 15 ---
    {
        const float2 my = pxy[w][k];
        const int nvg = nv[w];
        int dup = 0;
        for (int idx = 0; idx < nvg; ++idx) {
            const int k1 = vl[w][idx];
            if (k1 >= k) break;                       // list ascending
            const float2 p1 = pxy[w][k1];
            const float dx = p1.x - my.x, dy = p1.y - my.y;
            if (sqrtf(dx * dx + dy * dy) < 0.02f) dup = 1;
        }
        const int val = (km < npd[w][kd]) ? 1 : 0;
        const int kp = (val && !dup) ? 1 : 0;
        const unsigned long long bal = __ballot(kp);
        const int pref = (int)__popcll(bal << (63 - lane));
        if (lane == 63) kcv[w][half] = (int)__popcll(bal);
        __syncthreads();
        const int cnt = (half ? kcv[w][0] : 0) + pref;
        if (kp && cnt <= MAXO - 1) klist[w][cnt - 1] = k;
        if (lane == 0 && half == 0) {
            const int tot = kcv[w][0] + kcv[w][1];
            kcnt[w] = (tot < MAXO - 1) ? tot : (MAXO - 1);
        }
        __syncthreads();
    }

    // --- gather kept rows ---
    for (int idx = tid; idx < G * EL; idx += NTHR) {
        const int g = idx / EL, rem = idx % EL;
        const int s = rem / ORIG, c = rem % ORIG;
        if (s < kcnt[g]) {
            const int kk = klist[g][s], d = kk >> 4, m = kk & 15;
            float v;
            if (c < 16) v = elems_base[(size_t)jn[g][d] * EL + m * ORIG + c];
            else        v = (c == 16) ? pxy[g][kk].x : pxy[g][kk].y;
            kc[g][s][c] = v;
        }
    }
    __syncthreads();

    // --- hsum: thread (col,q) -> agent q over <=15 kept rows ---
    {
        float w1[ORIG];
#pragma unroll
        for (int c = 0; c < ORIG; ++c) w1[c] = menc_W1[c * EMBED + col];
        const float b1 = menc_b1[col];
        const int nk = kcnt[q];
        float hs = 0.f;
        for (int s = 0; s < nk; ++s) {
            const float4* mr = (const float4*)&kc[q][s][0];
            const float4 m0 = mr[0], m1 = mr[1], m2 = mr[2], m3 = mr[3];
            const float2 m4 = *(const float2*)&kc[q][s][16];
            float h = b1
                + m0.x*w1[0]  + m0.y*w1[1]  + m0.z*w1[2]  + m0.w*w1[3]
                + m1.x*w1[4]  + m1.y*w1[5]  + m1.z*w1[6]  + m1.w*w1[7]
                + m2.x*w1[8]  + m2.y*w1[9]  + m2.z*w1[10] + m2.w*w1[11]
                + m3.x*w1[12] + m3.y*w1[13] + m3.z*w1[14] + m3.w*w1[15]
                + m4.x*w1[16] + m4.y*w1[17];
            hs += fmaxf(h, 0.f);
        }
        ((float*)&Hs[col])[q] = hs;
    }
    __syncthreads();

    // --- merged = hsum@W2 + b2, split-K4 ---
    {
        float4 acc = {0.f, 0.f, 0.f, 0.f};
        const int c0 = 32 * q;
#pragma unroll 8
        for (int c = c0; c < c0 + 32; ++c) {
            const float4 s = Hs[c];
            const float  ww = menc_W2[c * EMBED + col];
            acc.x += s.x * ww; acc.y += s.y * ww; acc.z += s.z * ww; acc.w += s.w * ww;
        }
        Mp4[q][col] = acc;
    }
    __syncthreads();
    if (tid < EMBED) {
        const float4 a = Mp4[0][tid], b = Mp4[1][tid], c = Mp4[2][tid], d = Mp4[3][tid];
        const float bb = menc_b2[tid];
        float4 e;
        e.x = a.x + b.x + c.x + d.x + bb;
        e.y = a.y + b.y + c.y + d.y + bb;
        e.z = a.z + b.z + c.z + d.z + bb;
        e.w = a.w + b.w + c.w + d.w + bb;
        Mg[tid] = e;
    }
    __syncthreads();

    // --- n2 = argmax(merged@Ws + bs) ---
    if (tid < G * (MAXO + 1)) {
        const int g = tid / (MAXO + 1), qq = tid % (MAXO + 1);
        float v = dec_bs[qq];
        for (int c = 0; c < EMBED; ++c)
            v += ((const float*)&Mg[c])[g] * dec_Ws[c * (MAXO + 1) + qq];
        lg2[g][qq] = v;
    }
    __syncthreads();
    if (tid < G) {
        int best = 0; float bv = lg2[tid][0];
        for (int qq = 1; qq <= MAXO; ++qq) if (lg2[tid][qq] > bv) { bv = lg2[tid][qq]; best = qq; }
        n2s[tid] = best;
    }
    __syncthreads();

    // --- decode = merged@Wx + bx, split-K2 (576 units) ---
    {
        int u = tid;
        for (int pass = 0; pass < 2; ++pass) {
            if (u < 2 * EL) {
                const int h = (u >= EL) ? 1 : 0;
                const int e = u - h * EL;
                float4 acc = {0.f, 0.f, 0.f, 0.f};
                const int c0 = 64 * h;
#pragma unroll 8
                for (int c = c0; c < c0 + 64; ++c) {
                    const float4 s = Mg[c];
                    const float  ww = dec_Wx[c * EL + e];
                    acc.x += s.x * ww; acc.y += s.y * ww; acc.z += s.z * ww; acc.w += s.w * ww;
                }
                Pp[h][e] = acc;
            }
            u = NTHR + tid;
        }
    }
    __syncthreads();
    if (tid < EL) {
        const int m = tid / ORIG;
        const float4 a = Pp[0][tid], b = Pp[1][tid];
        const float bx = dec_bx[tid];
        out_dec[(size_t)(i0 + 0) * EL + tid] = (m < n2s[0]) ? (a.x + b.x + bx) : 0.f;
        out_dec[(size_t)(i0 + 1) * EL + tid] = (m < n2s[1]) ? (a.y + b.y + bx) : 0.f;
        out_dec[(size_t)(i0 + 2) * EL + tid] = (m < n2s[2]) ? (a.z + b.z + bx) : 0.f;
        out_dec[(size_t)(i0 + 3) * EL + tid] = (m < n2s[3]) ? (a.w + b.w + bx) : 0.f;
    } else if (tid >= NTHR - G * MAXO) {
        const int idx = tid - (NTHR - G * MAXO);
        const int g = idx >> 4, m = idx & 15;
        out_batch[(i0 + g) * MAXO + m] = (float)(i0 + g);
        out_mask[(i0 + g) * MAXO + m]  = (m < n2s[g]) ? 1.f : 0.f;
    }
}

extern "C" void kernel_launch(void* const* d_in, const int* in_sizes, int n_in,
                              void* d_out, int out_size, void* d_ws, size_t ws_size,
                              hipStream_t stream)
{
    const float* obj_x     = (const float*)d_in[0];
    const float* obj_pos   = (const float*)d_in[1];
    const float* agent_pos = (const float*)d_in[2];
    const float* enc_W1    = (const float*)d_in[3];
    const float* enc_b1    = (const float*)d_in[4];
    const float* enc_W2    = (const float*)d_in[5];
    const float* enc_b2    = (const float*)d_in[6];
    const float* mdec_Ws   = (const float*)d_in[7];
    const float* mdec_bs   = (const float*)d_in[8];
    const float* mdec_Wx   = (const float*)d_in[9];
    const float* mdec_bx   = (const float*)d_in[10];
    const float* menc_W1   = (const float*)d_in[11];
    const float* menc_b1   = (const float*)d_in[12];
    const float* menc_W2   = (const float*)d_in[13];
    const float* menc_b2   = (const float*)d_in[14];
    const float* dec_Ws    = (const float*)d_in[15];
    const float* dec_bs    = (const float*)d_in[16];
    const float* dec_Wx    = (const float*)d_in[17];
    const float* dec_bx    = (const float*)d_in[18];
    const int*   obs_edge  = (const int*)d_in[19];
    const int*   comm_edge = (const int*)d_in[20];

    float* elems_base = (float*)d_ws;                                   // 4096*288 f32
    int*   npred      = (int*)((char*)d_ws + (size_t)A_N * EL * sizeof(float));

    float* out_dec   = (float*)d_out;
    float* out_batch = out_dec + (size_t)A_N * EL;
    float* out_mask  = out_batch + (size_t)A_N * MAXO;

    enc512_kernel<<<NBLK, NTHR, 0, stream>>>(
        obj_x, obj_pos, agent_pos, enc_W1, enc_b1, enc_W2, enc_b2,
        mdec_Ws, mdec_bs, mdec_Wx, mdec_bx, obs_edge, elems_base, npred);

    merge512_kernel<<<NBLK, NTHR, 0, stream>>>(
        agent_pos, menc_W1, menc_b1, menc_W2, menc_b2,
        dec_Ws, dec_bs, dec_Wx, dec_bx, comm_edge,
        elems_base, npred, out_dec, out_batch, out_mask);
}

// Round 7
// 149.185 us; speedup vs baseline: 1.5210x; 1.0983x over previous
//
#include <hip/hip_runtime.h>

#define A_N   4096
#define EMBED 128
#define MAXO  16
#define DEG   8
#define OBSD  8
#define ORIG  18
#define KCAND 128            // DEG*MAXO candidates per agent
#define G     4              // agents per block
#define NBLK  (A_N / G)      // 1024 blocks
#define NTHR  512            // 8 waves/block -> 4 blocks/CU = 32 waves/CU
#define EL    (MAXO * ORIG)  // 288
#define THRES2 (0.02f * 0.02f)

// ---------------------------------------------------------------------------
// Kernel A: 4 source agents, 512 threads.
// thread (col=tid&127, q=tid>>7): agent q for row phases; split-K4 on W2;
// split-K2 (576 units) on the 288-wide elems GEMV; split-K4 logits.
// ---------------------------------------------------------------------------
__global__ __launch_bounds__(NTHR, 8) void enc512_kernel(
    const float* __restrict__ obj_x, const float* __restrict__ obj_pos,
    const float* __restrict__ agent_pos,
    const float* __restrict__ enc_W1, const float* __restrict__ enc_b1,
    const float* __restrict__ enc_W2, const float* __restrict__ enc_b2,
    const float* __restrict__ mdec_Ws, const float* __restrict__ mdec_bs,
    const float* __restrict__ mdec_Wx, const float* __restrict__ mdec_bx,
    const int* __restrict__ obs_edge,
    float* __restrict__ elems_base, int* __restrict__ npred_out)
{
    const int blk = blockIdx.x, tid = threadIdx.x;
    const int i0  = blk * G;
    const int col = tid & 127, q = tid >> 7;

    __shared__ int    on[G][OBSD];
    __shared__ float  msg[G * OBSD][20];
    __shared__ float4 SG[EMBED];          // [c] -> 4 agents
    __shared__ float4 Ep4[4][EMBED];      // split-K4 partials
    __shared__ float4 Eg[EMBED];
    __shared__ float  lgp[G][MAXO + 1][4];
    __shared__ float  lgts[G][MAXO + 1];
    __shared__ float4 Pp[2][EL];          // split-K2 partials for elems

    if (tid < G * OBSD) {
        const int g = tid >> 3, d = tid & 7;
        on[g][d] = obs_edge[A_N * OBSD + (i0 + g) * OBSD + d];
    }
    __syncthreads();
    for (int idx = tid; idx < G * OBSD * ORIG; idx += NTHR) {
        const int r = idx / ORIG, c = idx % ORIG;
        const int g = r >> 3, d = r & 7;
        const int o = on[g][d];
        float v;
        if (c < 16) v = obj_x[o * 16 + c];
        else        v = obj_pos[o * 2 + (c - 16)] - agent_pos[(i0 + g) * 2 + (c - 16)];
        msg[r][c] = v;
    }
    __syncthreads();

    // --- h = relu(msg@W1+b1), segment-sum; thread (col,q) -> agent q ---
    {
        float w1[ORIG];
#pragma unroll
        for (int c = 0; c < ORIG; ++c) w1[c] = enc_W1[c * EMBED + col];
        const float b1 = enc_b1[col];
        float acc = 0.f;
#pragma unroll
        for (int d = 0; d < OBSD; ++d) {
            const int r = q * OBSD + d;
            const float4* mr = (const float4*)&msg[r][0];
            const float4 m0 = mr[0], m1 = mr[1], m2 = mr[2], m3 = mr[3];
            const float2 m4 = *(const float2*)&msg[r][16];
            float h = b1
                + m0.x*w1[0]  + m0.y*w1[1]  + m0.z*w1[2]  + m0.w*w1[3]
                + m1.x*w1[4]  + m1.y*w1[5]  + m1.z*w1[6]  + m1.w*w1[7]
                + m2.x*w1[8]  + m2.y*w1[9]  + m2.z*w1[10] + m2.w*w1[11]
                + m3.x*w1[12] + m3.y*w1[13] + m3.z*w1[14] + m3.w*w1[15]
                + m4.x*w1[16] + m4.y*w1[17];
            acc += fmaxf(h, 0.f);
        }
        ((float*)&SG[col])[q] = acc;
    }
    __syncthreads();

    // --- enc = S@W2 + b2, split-K4 ---
    {
        float4 acc = {0.f, 0.f, 0.f, 0.f};
        const int c0 = 32 * q;
#pragma unroll 8
        for (int c = c0; c < c0 + 32; ++c) {
            const float4 s = SG[c];
            const float  w = enc_W2[c * EMBED + col];
            acc.x += s.x * w; acc.y += s.y * w; acc.z += s.z * w; acc.w += s.w * w;
        }
        Ep4[q][col] = acc;
    }
    __syncthreads();
    if (tid < EMBED) {
        const float4 a = Ep4[0][tid], b = Ep4[1][tid], c = Ep4[2][tid], d = Ep4[3][tid];
        const float bb = enc_b2[tid];
        float4 e;
        e.x = a.x + b.x + c.x + d.x + bb;
        e.y = a.y + b.y + c.y + d.y + bb;
        e.z = a.z + b.z + c.z + d.z + bb;
        e.w = a.w + b.w + c.w + d.w + bb;
        Eg[tid] = e;
    }
    __syncthreads();

    // --- npred logits, split-K4 over 272 threads ---
    {
        const int p = tid >> 7, rem = tid & 127;
        if (rem < G * (MAXO + 1)) {
            const int g = rem / (MAXO + 1), qq = rem % (MAXO + 1);
            float v = 0.f;
            const int c0 = 32 * p;
#pragma unroll 8
            for (int c = c0; c < c0 + 32; ++c)
                v += ((const float*)&Eg[c])[g] * mdec_Ws[c * (MAXO + 1) + qq];
            lgp[g][qq][p] = v;
        }
    }
    __syncthreads();
    if (tid < G * (MAXO + 1)) {
        const int g = tid / (MAXO + 1), qq = tid % (MAXO + 1);
        lgts[g][qq] = lgp[g][qq][0] + lgp[g][qq][1] + lgp[g][qq][2] + lgp[g][qq][3]
                    + mdec_bs[qq];
    }
    __syncthreads();
    if (tid < G) {
        int best = 0; float bv = lgts[tid][0];
        for (int qq = 1; qq <= MAXO; ++qq) if (lgts[tid][qq] > bv) { bv = lgts[tid][qq]; best = qq; }
        npred_out[i0 + tid] = best;
    }

    // --- elems = enc@Wx + bx, split-K2: 576 units over 512 threads ---
    {
        int u = tid;
        for (int pass = 0; pass < 2; ++pass) {
            if (u < 2 * EL) {
                const int h = (u >= EL) ? 1 : 0;
                const int e = u - h * EL;
                float4 acc = {0.f, 0.f, 0.f, 0.f};
                const int c0 = 64 * h;
#pragma unroll 8
                for (int c = c0; c < c0 + 64; ++c) {
                    const float4 s = Eg[c];
                    const float  w = mdec_Wx[c * EL + e];
                    acc.x += s.x * w; acc.y += s.y * w; acc.z += s.z * w; acc.w += s.w * w;
                }
                Pp[h][e] = acc;
            }
            u = NTHR + tid;      // second pass covers units 512..575 (tid<64)
        }
    }
    __syncthreads();
    if (tid < EL) {
        const float4 a = Pp[0][tid], b = Pp[1][tid];
        const float bx = mdec_bx[tid];
        elems_base[(size_t)(i0 + 0) * EL + tid] = a.x + b.x + bx;
        elems_base[(size_t)(i0 + 1) * EL + tid] = a.y + b.y + bx;
        elems_base[(size_t)(i0 + 2) * EL + tid] = a.z + b.z + bx;
        elems_base[(size_t)(i0 + 3) * EL + tid] = a.w + b.w + bx;
    }
}

// ---------------------------------------------------------------------------
// Kernel B: 4 target agents, 512 threads = 8 waves; wave-pair (w=wv>>1,
// half=wv&1) handles agent w's candidate half-tile for dedup phases.
// Dedup scans the COMPACTED (vl,pv) arrays: direct-indexed streams, no
// LDS-indirect chain, squared-distance compare (no sqrt).
// ---------------------------------------------------------------------------
__global__ __launch_bounds__(NTHR, 8) void merge512_kernel(
    const float* __restrict__ agent_pos,
    const float* __restrict__ menc_W1, const float* __restrict__ menc_b1,
    const float* __restrict__ menc_W2, const float* __restrict__ menc_b2,
    const float* __restrict__ dec_Ws, const float* __restrict__ dec_bs,
    const float* __restrict__ dec_Wx, const float* __restrict__ dec_bx,
    const int* __restrict__ comm_edge,
    const float* __restrict__ elems_base, const int* __restrict__ npred,
    float* __restrict__ out_dec, float* __restrict__ out_batch,
    float* __restrict__ out_mask)
{
    const int blk = blockIdx.x, tid = threadIdx.x;
    const int i0  = blk * G;
    const int col = tid & 127, q = tid >> 7;
    const int lane = tid & 63, wv = tid >> 6;
    const int w = wv >> 1, half = wv & 1;

    __shared__ int    jn[G][DEG];
    __shared__ float  relx[G][DEG], rely[G][DEG];
    __shared__ int    npd[G][DEG];
    __shared__ float2 pxy[G][KCAND];
    __shared__ int    vl[G][KCAND];      // compacted valid indices (ascending)
    __shared__ float2 pv[G][KCAND];      // compacted valid positions
    __shared__ int    wcv[G][2], kcv[G][2];
    __shared__ int    nv[G], kcnt[G];
    __shared__ int    klist[G][MAXO];
    __shared__ float  kc[G][MAXO][20];
    __shared__ float4 Hs[EMBED];
    __shared__ float4 Mp4[4][EMBED];
    __shared__ float4 Mg[EMBED];
    __shared__ float  lgp[G][MAXO + 1][4];
    __shared__ float  lg2[G][MAXO + 1];
    __shared__ int    n2s[G];
    __shared__ float4 Pp[2][EL];

    if (tid < G * DEG) {
        const int g = tid >> 3, d = tid & 7;
        const int e = (i0 + g) * DEG + d;
        const int j  = comm_edge[e];
        const int ii = comm_edge[A_N * DEG + e];
        jn[g][d]  = j;
        relx[g][d] = agent_pos[j * 2 + 0] - agent_pos[ii * 2 + 0];
        rely[g][d] = agent_pos[j * 2 + 1] - agent_pos[ii * 2 + 1];
        npd[g][d] = npred[j];
    }
    __syncthreads();

    // --- positions + valid, compacted valid list+positions ---
    const int k = 64 * half + lane;
    const int kd = k >> 4, km = k & 15;
    float2 p;
    int val;
    {
        const float* eb = elems_base + (size_t)jn[w][kd] * EL + km * ORIG;
        p = *(const float2*)(eb + 16);
        p.x += relx[w][kd]; p.y += rely[w][kd];
        pxy[w][k] = p;
        val = (km < npd[w][kd]) ? 1 : 0;
        const unsigned long long bal = __ballot(val);
        const int pref = (int)__popcll(bal << (63 - lane));
        if (lane == 63) wcv[w][half] = (int)__popcll(bal);
        __syncthreads();
        const int base = half ? wcv[w][0] : 0;
        if (val) { vl[w][base + pref - 1] = k; pv[w][base + pref - 1] = p; }
        if (lane == 0 && half == 0) nv[w] = wcv[w][0] + wcv[w][1];
        __syncthreads();
    }

    // --- dedup + cap 15: scan compacted streams (pipelined, no sqrt) ---
    {
        const int nvg = nv[w];
        int dup = 0;
        for (int idx = 0; idx < nvg; ++idx) {
            const int k1 = vl[w][idx];
            if (k1 >= k) break;                       // ascending list
            const float2 p1 = pv[w][idx];
            const float dx = p1.x - p.x, dy = p1.y - p.y;
            if (dx * dx + dy * dy < THRES2) dup = 1;
        }
        const int kp = (val && !dup) ? 1 : 0;
        const unsigned long long bal = __ballot(kp);
        const int pref = (int)__popcll(bal << (63 - lane));
        if (lane == 63) kcv[w][half] = (int)__popcll(bal);
        __syncthreads();
        const int cnt = (half ? kcv[w][0] : 0) + pref;
        if (kp && cnt <= MAXO - 1) klist[w][cnt - 1] = k;
        if (lane == 0 && half == 0) {
            const int tot = kcv[w][0] + kcv[w][1];
            kcnt[w] = (tot < MAXO - 1) ? tot : (MAXO - 1);
        }
        __syncthreads();
    }

    // --- gather kept rows ---
    for (int idx = tid; idx < G * EL; idx += NTHR) {
        const int g = idx / EL, rem = idx % EL;
        const int s = rem / ORIG, c = rem % ORIG;
        if (s < kcnt[g]) {
            const int kk = klist[g][s], d = kk >> 4, m = kk & 15;
            float v;
            if (c < 16) v = elems_base[(size_t)jn[g][d] * EL + m * ORIG + c];
            else        v = (c == 16) ? pxy[g][kk].x : pxy[g][kk].y;
            kc[g][s][c] = v;
        }
    }
    __syncthreads();

    // --- hsum: thread (col,q) -> agent q over <=15 kept rows ---
    {
        float w1[ORIG];
#pragma unroll
        for (int c = 0; c < ORIG; ++c) w1[c] = menc_W1[c * EMBED + col];
        const float b1 = menc_b1[col];
        const int nk = kcnt[q];
        float hs = 0.f;
        for (int s = 0; s < nk; ++s) {
            const float4* mr = (const float4*)&kc[q][s][0];
            const float4 m0 = mr[0], m1 = mr[1], m2 = mr[2], m3 = mr[3];
            const float2 m4 = *(const float2*)&kc[q][s][16];
            float h = b1
                + m0.x*w1[0]  + m0.y*w1[1]  + m0.z*w1[2]  + m0.w*w1[3]
                + m1.x*w1[4]  + m1.y*w1[5]  + m1.z*w1[6]  + m1.w*w1[7]
                + m2.x*w1[8]  + m2.y*w1[9]  + m2.z*w1[10] + m2.w*w1[11]
                + m3.x*w1[12] + m3.y*w1[13] + m3.z*w1[14] + m3.w*w1[15]
                + m4.x*w1[16] + m4.y*w1[17];
            hs += fmaxf(h, 0.f);
        }
        ((float*)&Hs[col])[q] = hs;
    }
    __syncthreads();

    // --- merged = hsum@W2 + b2, split-K4 ---
    {
        float4 acc = {0.f, 0.f, 0.f, 0.f};
        const int c0 = 32 * q;
#pragma unroll 8
        for (int c = c0; c < c0 + 32; ++c) {
            const float4 s = Hs[c];
            const float  ww = menc_W2[c * EMBED + col];
            acc.x += s.x * ww; acc.y += s.y * ww; acc.z += s.z * ww; acc.w += s.w * ww;
        }
        Mp4[q][col] = acc;
    }
    __syncthreads();
    if (tid < EMBED) {
        const float4 a = Mp4[0][tid], b = Mp4[1][tid], c = Mp4[2][tid], d = Mp4[3][tid];
        const float bb = menc_b2[tid];
        float4 e;
        e.x = a.x + b.x + c.x + d.x + bb;
        e.y = a.y + b.y + c.y + d.y + bb;
        e.z = a.z + b.z + c.z + d.z + bb;
        e.w = a.w + b.w + c.w + d.w + bb;
        Mg[tid] = e;
    }
    __syncthreads();

    // --- n2 logits, split-K4 over 272 threads ---
    {
        const int pp = tid >> 7, rem = tid & 127;
        if (rem < G * (MAXO + 1)) {
            const int g = rem / (MAXO + 1), qq = rem % (MAXO + 1);
            float v = 0.f;
            const int c0 = 32 * pp;
#pragma unroll 8
            for (int c = c0; c < c0 + 32; ++c)
                v += ((const float*)&Mg[c])[g] * dec_Ws[c * (MAXO + 1) + qq];
            lgp[g][qq][pp] = v;
        }
    }
    __syncthreads();
    if (tid < G * (MAXO + 1)) {
        const int g = tid / (MAXO + 1), qq = tid % (MAXO + 1);
        lg2[g][qq] = lgp[g][qq][0] + lgp[g][qq][1] + lgp[g][qq][2] + lgp[g][qq][3]
                   + dec_bs[qq];
    }
    __syncthreads();
    if (tid < G) {
        int best = 0; float bv = lg2[tid][0];
        for (int qq = 1; qq <= MAXO; ++qq) if (lg2[tid][qq] > bv) { bv = lg2[tid][qq]; best = qq; }
        n2s[tid] = best;
    }
    __syncthreads();

    // --- decode = merged@Wx + bx, split-K2 (576 units) ---
    {
        int u = tid;
        for (int pass = 0; pass < 2; ++pass) {
            if (u < 2 * EL) {
                const int h = (u >= EL) ? 1 : 0;
                const int e = u - h * EL;
                float4 acc = {0.f, 0.f, 0.f, 0.f};
                const int c0 = 64 * h;
#pragma unroll 8
                for (int c = c0; c < c0 + 64; ++c) {
                    const float4 s = Mg[c];
                    const float  ww = dec_Wx[c * EL + e];
                    acc.x += s.x * ww; acc.y += s.y * ww; acc.z += s.z * ww; acc.w += s.w * ww;
                }
                Pp[h][e] = acc;
            }
            u = NTHR + tid;
        }
    }
    __syncthreads();
    if (tid < EL) {
        const int m = tid / ORIG;
        const float4 a = Pp[0][tid], b = Pp[1][tid];
        const float bx = dec_bx[tid];
        out_dec[(size_t)(i0 + 0) * EL + tid] = (m < n2s[0]) ? (a.x + b.x + bx) : 0.f;
        out_dec[(size_t)(i0 + 1) * EL + tid] = (m < n2s[1]) ? (a.y + b.y + bx) : 0.f;
        out_dec[(size_t)(i0 + 2) * EL + tid] = (m < n2s[2]) ? (a.z + b.z + bx) : 0.f;
        out_dec[(size_t)(i0 + 3) * EL + tid] = (m < n2s[3]) ? (a.w + b.w + bx) : 0.f;
    } else if (tid >= NTHR - G * MAXO) {
        const int idx = tid - (NTHR - G * MAXO);
        const int g = idx >> 4, m = idx & 15;
        out_batch[(i0 + g) * MAXO + m] = (float)(i0 + g);
        out_mask[(i0 + g) * MAXO + m]  = (m < n2s[g]) ? 1.f : 0.f;
    }
}

extern "C" void kernel_launch(void* const* d_in, const int* in_sizes, int n_in,
                              void* d_out, int out_size, void* d_ws, size_t ws_size,
                              hipStream_t stream)
{
    const float* obj_x     = (const float*)d_in[0];
    const float* obj_pos   = (const float*)d_in[1];
    const float* agent_pos = (const float*)d_in[2];
    const float* enc_W1    = (const float*)d_in[3];
    const float* enc_b1    = (const float*)d_in[4];
    const float* enc_W2    = (const float*)d_in[5];
    const float* enc_b2    = (const float*)d_in[6];
    const float* mdec_Ws   = (const float*)d_in[7];
    const float* mdec_bs   = (const float*)d_in[8];
    const float* mdec_Wx   = (const float*)d_in[9];
    const float* mdec_bx   = (const float*)d_in[10];
    const float* menc_W1   = (const float*)d_in[11];
    const float* menc_b1   = (const float*)d_in[12];
    const float* menc_W2   = (const float*)d_in[13];
    const float* menc_b2   = (const float*)d_in[14];
    const float* dec_Ws    = (const float*)d_in[15];
    const float* dec_bs    = (const float*)d_in[16];
    const float* dec_Wx    = (const float*)d_in[17];
    const float* dec_bx    = (const float*)d_in[18];
    const int*   obs_edge  = (const int*)d_in[19];
    const int*   comm_edge = (const int*)d_in[20];

    float* elems_base = (float*)d_ws;                                   // 4096*288 f32
    int*   npred      = (int*)((char*)d_ws + (size_t)A_N * EL * sizeof(float));

    float* out_dec   = (float*)d_out;
    float* out_batch = out_dec + (size_t)A_N * EL;
    float* out_mask  = out_batch + (size_t)A_N * MAXO;

    enc512_kernel<<<NBLK, NTHR, 0, stream>>>(
        obj_x, obj_pos, agent_pos, enc_W1, enc_b1, enc_W2, enc_b2,
        mdec_Ws, mdec_bs, mdec_Wx, mdec_bx, obs_edge, elems_base, npred);

    merge512_kernel<<<NBLK, NTHR, 0, stream>>>(
        agent_pos, menc_W1, menc_b1, menc_W2, menc_b2,
        dec_Ws, dec_bs, dec_Wx, dec_bx, comm_edge,
        elems_base, npred, out_dec, out_batch, out_mask);
}